// Round 7
// baseline (3400.609 us; speedup 1.0000x reference)
//
#include <hip/hip_runtime.h>
#include <cstdint>

#define B_SZ 256
#define T_SEQ 512
#define I_SZ 256
#define H_SZ 512
#define O_SZ 256

typedef short shortx8 __attribute__((ext_vector_type(8)));
typedef float floatx4 __attribute__((ext_vector_type(4)));
typedef unsigned int uintx4 __attribute__((ext_vector_type(4)));

#define SENT 0xFFFFFFFFu  // bf16 NaN|NaN — unreachable for h in (-1,1)

__device__ __forceinline__ unsigned short f2bf(float f) {
  uint32_t u = __float_as_uint(f);
  u = u + 0x7fffu + ((u >> 16) & 1u);   // RNE
  return (unsigned short)(u >> 16);
}
__device__ __forceinline__ float bf2f(unsigned short h) {
  return __uint_as_float(((uint32_t)h) << 16);
}
__device__ __forceinline__ float sigm(float x) { return 1.0f / (1.0f + __expf(-x)); }
__device__ __forceinline__ float tanh_fast(float x) {
  x = fminf(15.0f, fmaxf(-15.0f, x));
  float e = __expf(2.0f * x);
  return (e - 1.0f) / (e + 1.0f);
}
__device__ __forceinline__ uint32_t umax_(uint32_t a, uint32_t b) {
  return a > b ? a : b;
}
__device__ __forceinline__ uintx4 umax4_(uintx4 a, uintx4 b) {
  uintx4 r;
  r.x = umax_(a.x, b.x); r.y = umax_(a.y, b.y);
  r.z = umax_(a.z, b.z); r.w = umax_(a.w, b.w);
  return r;
}

// ---------------------------------------------------------------------------
// Phase 0: pack weights (wxt transposed col-major, from round 3).
// ---------------------------------------------------------------------------
__global__ __launch_bounds__(256) void pack_kernel(
    const float* __restrict__ Wf, const float* __restrict__ Wi,
    const float* __restrict__ Wc, const float* __restrict__ Wo,
    const float* __restrict__ bf, const float* __restrict__ bi,
    const float* __restrict__ bc, const float* __restrict__ bo,
    unsigned short* __restrict__ whf, unsigned short* __restrict__ wxt,
    float* __restrict__ bias) {
  int idx = blockIdx.x * 256 + threadIdx.x;
  if (idx < 2048) {
    int g = idx >> 9, hid = idx & 511;
    const float* bp = (g == 0) ? bf : (g == 1) ? bi : (g == 2) ? bc : bo;
    bias[idx] = bp[hid];
  }
  int i2 = idx - 2048;
  if (i2 >= 0 && i2 < 256 * 2048) {
    int k = i2 >> 11, col = i2 & 2047, g = col >> 9, hid = col & 511;
    const float* Wp = (g == 0) ? Wf : (g == 1) ? Wi : (g == 2) ? Wc : Wo;
    wxt[(size_t)col * 256 + k] = f2bf(Wp[k * 512 + hid]);   // transposed
  }
  int i3 = i2 - 256 * 2048;
  if (i3 >= 0 && i3 < 1048576) {
    int j = i3 & 7, l = (i3 >> 3) & 63, ks = (i3 >> 9) & 15;
    int nt = (i3 >> 13) & 1, g = (i3 >> 14) & 3, cg = (i3 >> 16) & 15;
    int k = ks * 32 + (l >> 4) * 8 + j;
    int hid = cg * 32 + nt * 16 + (l & 15);
    const float* Wp = (g == 0) ? Wf : (g == 1) ? Wi : (g == 2) ? Wc : Wo;
    whf[i3] = f2bf(Wp[(256 + k) * 512 + hid]);
  }
}

// Init: h slot 0 = zeros (h0) on BOTH rails, c state = zeros.
__global__ __launch_bounds__(256) void init_kernel(uint32_t* h_ex,
                                                   uint32_t* h_l2,
                                                   float* c_gl) {
  int idx = blockIdx.x * 256 + threadIdx.x;
  if (idx < 65536) { h_ex[idx] = 0u; h_l2[idx] = 0u; }
  if (idx < 131072) c_gl[idx] = 0.0f;
}

// Poison: sentinel-fill all TCp1 slots EXCEPT the live one, on BOTH rails.
__global__ __launch_bounds__(256) void poison_kernel(uint32_t* h_ex,
                                                     uint32_t* h_l2, int live,
                                                     int TCp1) {
  size_t idx = (size_t)blockIdx.x * 256 + threadIdx.x;
  if (idx >= (size_t)TCp1 * 16384) return;
  int slot = (int)(idx >> 14);
  if (slot == live) return;
  ((uint4*)h_ex)[idx] = make_uint4(SENT, SENT, SENT, SENT);
  ((uint4*)h_l2)[idx] = make_uint4(SENT, SENT, SENT, SENT);
}

// ---------------------------------------------------------------------------
// Phase 1: Z = X @ Wx + bias (bf16 out). Round-3 version. Unchanged.
// ---------------------------------------------------------------------------
__global__ __launch_bounds__(256) void gemm_x(
    const float* __restrict__ X, const unsigned short* __restrict__ Wxt,
    const float* __restrict__ bias, unsigned short* __restrict__ Z,
    int t0, int TC, int tcs) {
  __shared__ __align__(16) unsigned short smem[17408];
  unsigned short* lds_a = smem;          // [ks8][row][8]
  unsigned short* lds_b = smem + 8192;   // [ks8][col][8]
  unsigned short* lds_t = smem;          // [row][136] epilogue

  const int tid = threadIdx.x;
  const int mt = blockIdx.x >> 4, ntb = blockIdx.x & 15;
  const int n0 = ntb * 128;
  const int w = tid >> 6, l = tid & 63, q = l >> 4, n15 = l & 15;

  floatx4 acc[2][8];
#pragma unroll
  for (int a = 0; a < 2; ++a)
#pragma unroll
    for (int nb = 0; nb < 8; ++nb) acc[a][nb] = (floatx4){0.f, 0.f, 0.f, 0.f};

  const int a_row = tid & 127, a_h = tid >> 7;
  const int Mr_st = mt * 128 + a_row;
  const int bb = Mr_st >> tcs, tt = Mr_st & (TC - 1);
  const float* asrc = X + ((size_t)(bb * T_SEQ + t0 + tt)) * I_SZ;

  for (int ko = 0; ko < 4; ++ko) {
    const int k0 = ko * 64;
    __syncthreads();
#pragma unroll
    for (int i = 0; i < 4; ++i) {
      int g = i * 256 + tid;
      int ks8 = g >> 7, col = g & 127;
      const unsigned short* gsrc =
          Wxt + (size_t)(n0 + col) * 256 + k0 + ks8 * 8;
      __builtin_amdgcn_global_load_lds(
          (const __attribute__((address_space(1))) void*)gsrc,
          (__attribute__((address_space(3))) void*)(lds_b + (size_t)g * 8),
          16, 0, 0);
    }
#pragma unroll
    for (int i = 0; i < 4; ++i) {
      int ks8 = 2 * i + a_h;
      int kl = ks8 * 8;
      float4 v0 = *(const float4*)(asrc + k0 + kl);
      float4 v1 = *(const float4*)(asrc + k0 + kl + 4);
      uint4 pk;
      pk.x = (uint32_t)f2bf(v0.x) | ((uint32_t)f2bf(v0.y) << 16);
      pk.y = (uint32_t)f2bf(v0.z) | ((uint32_t)f2bf(v0.w) << 16);
      pk.z = (uint32_t)f2bf(v1.x) | ((uint32_t)f2bf(v1.y) << 16);
      pk.w = (uint32_t)f2bf(v1.z) | ((uint32_t)f2bf(v1.w) << 16);
      *(uint4*)(lds_a + ((size_t)ks8 * 128 + a_row) * 8) = pk;
    }
    __syncthreads();
#pragma unroll
    for (int kk = 0; kk < 2; ++kk) {
      const int ks8 = kk * 4 + q;
      shortx8 af[2], bfr[8];
#pragma unroll
      for (int a = 0; a < 2; ++a) {
        int row = (w * 2 + a) * 16 + n15;
        af[a] = *(const shortx8*)(lds_a + ((size_t)ks8 * 128 + row) * 8);
      }
#pragma unroll
      for (int nb = 0; nb < 8; ++nb) {
        int col = nb * 16 + n15;
        bfr[nb] = *(const shortx8*)(lds_b + ((size_t)ks8 * 128 + col) * 8);
      }
#pragma unroll
      for (int a = 0; a < 2; ++a)
#pragma unroll
        for (int nb = 0; nb < 8; ++nb)
          acc[a][nb] = __builtin_amdgcn_mfma_f32_16x16x32_bf16(
              af[a], bfr[nb], acc[a][nb], 0, 0, 0);
    }
  }
  __syncthreads();
#pragma unroll
  for (int a = 0; a < 2; ++a) {
#pragma unroll
    for (int nb = 0; nb < 8; ++nb) {
      int colg = n0 + nb * 16 + n15;
      float bv = bias[colg];
      floatx4 v = acc[a][nb];
#pragma unroll
      for (int r = 0; r < 4; ++r) {
        int row = (w * 2 + a) * 16 + q * 4 + r;
        lds_t[row * 136 + nb * 16 + n15] = f2bf(v[r] + bv);
      }
    }
  }
  __syncthreads();
#pragma unroll
  for (int i = 0; i < 8; ++i) {
    int g2 = i * 256 + tid;
    int row = g2 >> 4, c8 = (g2 & 15) * 8;
    shortx8 v = *(const shortx8*)(lds_t + row * 136 + c8);
    int Mr2 = mt * 128 + row;
    *(shortx8*)(Z + (size_t)Mr2 * 2048 + n0 + c8) = v;
  }
}

// ---------------------------------------------------------------------------
// Phase 2: recurrent chunk — NEW this round: L2 rail is the DATA rail.
//  - round-1 poll structure restored (all lanes load all 16 chunks; the
//    poll values ARE the Af fragments — no reload, no extra barrier), but
//    pointed at h_l2 with sc0 (local-XCD L2 latency ~300cy vs IC ~900cy).
//  - producer stores h on BOTH rails (plain write-back -> local L2 line;
//    sc0 sc1 -> IC). r2's trap doesn't apply: poll never uses L1 (sc0
//    bypasses it), and the L2 line IS updated by the plain store when
//    producer+consumer share the XCD (r6 verified this mechanism).
//  - placement-independence: after 8 L2 rounds the poll escalates to the
//    IC rail (sc0 sc1, the r1/r3 proven path). Mixed-rail values are fine:
//    any non-SENT dword is final data on either rail. Worst case = today's
//    behavior; no hang, no staleness.
// ---------------------------------------------------------------------------
__global__ __launch_bounds__(256, 1) void lstm_chunk(
    const unsigned short* __restrict__ Z, const unsigned short* __restrict__ whf,
    uint32_t* h_ex, uint32_t* h_l2, float* c_gl, int t0, int TC) {
  __shared__ unsigned short wlds[65536];   // 128 KiB weight panel
  __shared__ float gl[2][4][16][32];       // 16 KiB gate exchange (dbuf)
  const int tid = threadIdx.x, l = tid & 63, w = tid >> 6, q = l >> 4,
            n15 = l & 15;
  // XCD-local relabel: peers of a bg group share blockIdx%8.
  const int idx = blockIdx.x;
  const int bg = (idx & 7) * 2 + ((idx >> 7) & 1);
  const int cg = (idx >> 3) & 15;

  __builtin_amdgcn_fence(__ATOMIC_ACQUIRE, "");  // drop stale L1/L2 lines

  {  // one-time: copy this block's contiguous 128 KiB panel into LDS
    const uint4* src = (const uint4*)(whf + (size_t)cg * 65536);
    uint4* dst = (uint4*)wlds;
#pragma unroll
    for (int i = 0; i < 32; ++i) dst[i * 256 + tid] = src[i * 256 + tid];
  }
  __syncthreads();

  const int m_e = tid >> 4, c2 = (tid & 15) * 2;
  const int b_e = bg * 16 + m_e;
  float cs0 = c_gl[b_e * 512 + cg * 32 + c2];
  float cs1 = c_gl[b_e * 512 + cg * 32 + c2 + 1];

  const unsigned short* wb0 = wlds + w * 16384;  // [ks][lane][8], nt=0
  const unsigned short* wb1 = wb0 + 8192;        // nt=1
  const int TCp1 = TC + 1;
  int sr = t0 % TCp1;  // read slot for step t

  // per-lane element offset (shorts) of Af ks=0 within a slot; ks-stride=512
  const size_t afoff = ((size_t)(bg * 64 + q) * 16 + n15) * 8;

  for (int t = t0; t < t0 + TC; ++t) {
    int sw = sr + 1;
    if (sw == TCp1) sw = 0;
    // Z prefetch (cached; issued before the poll, waited inside it)
    float zv[8];
#pragma unroll
    for (int nt = 0; nt < 2; ++nt)
#pragma unroll
      for (int r = 0; r < 4; ++r)
        zv[nt * 4 + r] =
            bf2f(Z[((size_t)(bg * 16 + q * 4 + r) * TC + (t - t0)) * 2048 +
                   w * 512 + cg * 32 + nt * 16 + n15]);
    // B prefetch ks 0..7 (LDS; overlaps the poll)
    shortx8 bp0[8], bp1[8];
#pragma unroll
    for (int ks = 0; ks < 8; ++ks) {
      bp0[ks] = *(const shortx8*)(wb0 + ks * 512 + l * 8);
      bp1[ks] = *(const shortx8*)(wb1 + ks * 512 + l * 8);
    }

    // ---- data-rail poll on the L2 rail (sc0); escalate to IC after 8 ----
    const unsigned short* pl2 =
        (const unsigned short*)(h_l2 + (size_t)sr * 65536) + afoff;
    const unsigned short* pic =
        (const unsigned short*)(h_ex + (size_t)sr * 65536) + afoff;
    uintx4 A0, A1, A2, A3, A4, A5, A6, A7, A8, A9, A10, A11, A12, A13, A14, A15;
    uint32_t mx;
    int spins = 0;
    do {
      if (spins < 8) {
        asm volatile(
            "global_load_dwordx4 %0, %16, off sc0\n\t"
            "global_load_dwordx4 %1, %16, off offset:1024 sc0\n\t"
            "global_load_dwordx4 %2, %16, off offset:2048 sc0\n\t"
            "global_load_dwordx4 %3, %16, off offset:3072 sc0\n\t"
            "global_load_dwordx4 %4, %17, off sc0\n\t"
            "global_load_dwordx4 %5, %17, off offset:1024 sc0\n\t"
            "global_load_dwordx4 %6, %17, off offset:2048 sc0\n\t"
            "global_load_dwordx4 %7, %17, off offset:3072 sc0\n\t"
            "global_load_dwordx4 %8, %18, off sc0\n\t"
            "global_load_dwordx4 %9, %18, off offset:1024 sc0\n\t"
            "global_load_dwordx4 %10, %18, off offset:2048 sc0\n\t"
            "global_load_dwordx4 %11, %18, off offset:3072 sc0\n\t"
            "global_load_dwordx4 %12, %19, off sc0\n\t"
            "global_load_dwordx4 %13, %19, off offset:1024 sc0\n\t"
            "global_load_dwordx4 %14, %19, off offset:2048 sc0\n\t"
            "global_load_dwordx4 %15, %19, off offset:3072 sc0\n\t"
            "s_waitcnt vmcnt(0)"
            : "=v"(A0), "=v"(A1), "=v"(A2), "=v"(A3), "=v"(A4), "=v"(A5),
              "=v"(A6), "=v"(A7), "=v"(A8), "=v"(A9), "=v"(A10), "=v"(A11),
              "=v"(A12), "=v"(A13), "=v"(A14), "=v"(A15)
            : "v"(pl2), "v"(pl2 + 2048), "v"(pl2 + 4096), "v"(pl2 + 6144)
            : "memory");
      } else {
        asm volatile(
            "global_load_dwordx4 %0, %16, off sc0 sc1\n\t"
            "global_load_dwordx4 %1, %16, off offset:1024 sc0 sc1\n\t"
            "global_load_dwordx4 %2, %16, off offset:2048 sc0 sc1\n\t"
            "global_load_dwordx4 %3, %16, off offset:3072 sc0 sc1\n\t"
            "global_load_dwordx4 %4, %17, off sc0 sc1\n\t"
            "global_load_dwordx4 %5, %17, off offset:1024 sc0 sc1\n\t"
            "global_load_dwordx4 %6, %17, off offset:2048 sc0 sc1\n\t"
            "global_load_dwordx4 %7, %17, off offset:3072 sc0 sc1\n\t"
            "global_load_dwordx4 %8, %18, off sc0 sc1\n\t"
            "global_load_dwordx4 %9, %18, off offset:1024 sc0 sc1\n\t"
            "global_load_dwordx4 %10, %18, off offset:2048 sc0 sc1\n\t"
            "global_load_dwordx4 %11, %18, off offset:3072 sc0 sc1\n\t"
            "global_load_dwordx4 %12, %19, off sc0 sc1\n\t"
            "global_load_dwordx4 %13, %19, off offset:1024 sc0 sc1\n\t"
            "global_load_dwordx4 %14, %19, off offset:2048 sc0 sc1\n\t"
            "global_load_dwordx4 %15, %19, off offset:3072 sc0 sc1\n\t"
            "s_waitcnt vmcnt(0)"
            : "=v"(A0), "=v"(A1), "=v"(A2), "=v"(A3), "=v"(A4), "=v"(A5),
              "=v"(A6), "=v"(A7), "=v"(A8), "=v"(A9), "=v"(A10), "=v"(A11),
              "=v"(A12), "=v"(A13), "=v"(A14), "=v"(A15)
            : "v"(pic), "v"(pic + 2048), "v"(pic + 4096), "v"(pic + 6144)
            : "memory");
      }
      uintx4 m = umax4_(umax4_(umax4_(A0, A1), umax4_(A2, A3)),
                        umax4_(umax4_(A4, A5), umax4_(A6, A7)));
      m = umax4_(m, umax4_(umax4_(A8, A9), umax4_(A10, A11)));
      m = umax4_(m, umax4_(umax4_(A12, A13), umax4_(A14, A15)));
      mx = umax_(umax_(m.x, m.y), umax_(m.z, m.w));
      ++spins;
    } while (__any(mx == SENT));

    uintx4 Au[16] = {A0, A1, A2,  A3,  A4,  A5,  A6,  A7,
                     A8, A9, A10, A11, A12, A13, A14, A15};
    floatx4 a0 = (floatx4){0.f, 0.f, 0.f, 0.f};
    floatx4 a1 = (floatx4){0.f, 0.f, 0.f, 0.f};
#pragma unroll
    for (int ks = 0; ks < 8; ++ks) {
      shortx8 af = *(shortx8*)&Au[ks];
      a0 = __builtin_amdgcn_mfma_f32_16x16x32_bf16(af, bp0[ks], a0, 0, 0, 0);
      a1 = __builtin_amdgcn_mfma_f32_16x16x32_bf16(af, bp1[ks], a1, 0, 0, 0);
    }
#pragma unroll
    for (int ks = 8; ks < 16; ++ks) {
      shortx8 af = *(shortx8*)&Au[ks];
      shortx8 tb0 = *(const shortx8*)(wb0 + ks * 512 + l * 8);
      shortx8 tb1 = *(const shortx8*)(wb1 + ks * 512 + l * 8);
      a0 = __builtin_amdgcn_mfma_f32_16x16x32_bf16(af, tb0, a0, 0, 0, 0);
      a1 = __builtin_amdgcn_mfma_f32_16x16x32_bf16(af, tb1, a1, 0, 0, 0);
    }
    // gate nonlinearity, publish to LDS (buffer t&1)
    const int pb = t & 1;
#pragma unroll
    for (int i = 0; i < 8; ++i) {
      float x = ((i < 4) ? a0[i & 3] : a1[i & 3]) + zv[i];
      float gv = (w == 2) ? tanh_fast(x) : sigm(x);
      gl[pb][w][q * 4 + (i & 3)][(i >> 2) * 16 + n15] = gv;
    }
    __syncthreads();
    {
      float f0 = gl[pb][0][m_e][c2], f1 = gl[pb][0][m_e][c2 + 1];
      float i0 = gl[pb][1][m_e][c2], i1 = gl[pb][1][m_e][c2 + 1];
      float g0 = gl[pb][2][m_e][c2], g1 = gl[pb][2][m_e][c2 + 1];
      float o0 = gl[pb][3][m_e][c2], o1 = gl[pb][3][m_e][c2 + 1];
      cs0 = f0 * cs0 + i0 * g0;
      cs1 = f1 * cs1 + i1 * g1;
      float h0 = o0 * tanh_fast(cs0);
      float h1 = o1 * tanh_fast(cs1);
      uint32_t hw = (uint32_t)f2bf(h0) | ((uint32_t)f2bf(h1) << 16);
      size_t widx = (size_t)sw * 65536 +
                    (size_t)(((bg * 16 + cg) * 4 + (c2 >> 3)) * 16 + m_e) * 4 +
                    ((c2 & 7) >> 1);
      // rail 2 first: plain write-back store — updates the local L2 line
      uint32_t* pl2w = h_l2 + widx;
      asm volatile("global_store_dword %0, %1, off"
                   :
                   : "v"(pl2w), "v"(hw)
                   : "memory");
      // rail 1: IC (system scope, guaranteed) — escalation + out_kernel path
      __hip_atomic_store(h_ex + widx, hw, __ATOMIC_RELAXED,
                         __HIP_MEMORY_SCOPE_SYSTEM);
    }
    sr = sw;
  }
  c_gl[b_e * 512 + cg * 32 + c2] = cs0;
  c_gl[b_e * 512 + cg * 32 + c2 + 1] = cs1;
}

// ---------------------------------------------------------------------------
// Phase 3: logits + log_softmax (reads final h slot on the IC rail).
// ---------------------------------------------------------------------------
__global__ __launch_bounds__(256) void out_kernel(
    const uint32_t* __restrict__ hfin, const float* __restrict__ Wout,
    const float* __restrict__ bout, float* __restrict__ out) {
  const int b = blockIdx.x, tid = threadIdx.x;
  __shared__ float hrow[512];
  if (tid < 64) {
    int ks = tid >> 2, qq = tid & 3;
    const uint4* h4 = (const uint4*)hfin;
    uint4 v = h4[((((size_t)(b >> 4)) * 16 + ks) * 4 + qq) * 16 + (b & 15)];
    uint32_t u[4] = {v.x, v.y, v.z, v.w};
#pragma unroll
    for (int d = 0; d < 4; ++d) {
      hrow[ks * 32 + qq * 8 + d * 2] = bf2f((unsigned short)(u[d] & 0xffff));
      hrow[ks * 32 + qq * 8 + d * 2 + 1] = bf2f((unsigned short)(u[d] >> 16));
    }
  }
  __syncthreads();
  float acc = bout[tid];
  for (int k = 0; k < 512; ++k) acc += hrow[k] * Wout[k * 256 + tid];
  __shared__ float red[256];
  red[tid] = acc;
  __syncthreads();
  for (int s = 128; s > 0; s >>= 1) {
    if (tid < s) red[tid] = fmaxf(red[tid], red[tid + s]);
    __syncthreads();
  }
  float mx = red[0];
  __syncthreads();
  red[tid] = __expf(acc - mx);
  __syncthreads();
  for (int s = 128; s > 0; s >>= 1) {
    if (tid < s) red[tid] += red[tid + s];
    __syncthreads();
  }
  out[b * 256 + tid] = acc - mx - logf(red[0]);
}

// ---------------------------------------------------------------------------
extern "C" void kernel_launch(void* const* d_in, const int* in_sizes, int n_in,
                              void* d_out, int out_size, void* d_ws,
                              size_t ws_size, hipStream_t stream) {
  const float* X = (const float*)d_in[0];
  const float* Wf = (const float*)d_in[1];
  const float* bf = (const float*)d_in[2];
  const float* Wi = (const float*)d_in[3];
  const float* bi = (const float*)d_in[4];
  const float* Wc = (const float*)d_in[5];
  const float* bc = (const float*)d_in[6];
  const float* Wo = (const float*)d_in[7];
  const float* bo = (const float*)d_in[8];
  const float* Wout = (const float*)d_in[9];
  const float* bout = (const float*)d_in[10];

  char* ws = (char*)d_ws;
  unsigned short* whf = (unsigned short*)(ws + 0x000000);   // 2 MiB
  unsigned short* wxt = (unsigned short*)(ws + 0x200000);   // 1 MiB (transposed)
  float* bias = (float*)(ws + 0x300000);                    // 8 KiB
  float* c_gl = (float*)(ws + 0x310000);                    // 512 KiB
  uint32_t* h_ex = (uint32_t*)(ws + 0x400000);              // 257 x 256 KiB (IC rail)
  uint32_t* h_l2 = (uint32_t*)(ws + 0x4500000);             // 257 x 256 KiB (L2 rail)
  const size_t zoff = 0x8600000;                            // 134 MiB
  unsigned short* Z = (unsigned short*)(ws + zoff);         // TC MiB

  int TC = 256;
  while (TC > 16 && zoff + ((size_t)B_SZ * TC * 2048 * 2) > ws_size) TC >>= 1;
  int tcs = 0;
  while ((1 << tcs) < TC) ++tcs;
  const int TCp1 = TC + 1;

  pack_kernel<<<(2048 + 256 * 2048 + 1048576 + 255) / 256, 256, 0, stream>>>(
      Wf, Wi, Wc, Wo, bf, bi, bc, bo, whf, wxt, bias);
  init_kernel<<<512, 256, 0, stream>>>(h_ex, h_l2, c_gl);

  for (int t0 = 0; t0 < T_SEQ; t0 += TC) {
    poison_kernel<<<(TCp1 * 16384 + 255) / 256, 256, 0, stream>>>(
        h_ex, h_l2, t0 % TCp1, TCp1);
    gemm_x<<<(B_SZ * TC / 128) * 16, 256, 0, stream>>>(X, wxt, bias, Z, t0, TC,
                                                       tcs);
    lstm_chunk<<<256, 256, 0, stream>>>(Z, whf, h_ex, h_l2, c_gl, t0, TC);
  }
  const int sfin = T_SEQ % TCp1;
  out_kernel<<<256, 256, 0, stream>>>(h_ex + (size_t)sfin * 65536, Wout, bout,
                                      (float*)d_out);
}

// Round 8
// 1978.184 us; speedup vs baseline: 1.7191x; 1.7191x over previous
//
#include <hip/hip_runtime.h>
#include <cstdint>

#define B_SZ 256
#define T_SEQ 512
#define I_SZ 256
#define H_SZ 512
#define O_SZ 256

typedef short shortx8 __attribute__((ext_vector_type(8)));
typedef float floatx4 __attribute__((ext_vector_type(4)));
typedef unsigned int uintx4 __attribute__((ext_vector_type(4)));

#define SENT 0xFFFFFFFFu  // bf16 NaN|NaN — unreachable for h in (-1,1)

__device__ __forceinline__ unsigned short f2bf(float f) {
  uint32_t u = __float_as_uint(f);
  u = u + 0x7fffu + ((u >> 16) & 1u);   // RNE
  return (unsigned short)(u >> 16);
}
__device__ __forceinline__ float bf2f(unsigned short h) {
  return __uint_as_float(((uint32_t)h) << 16);
}
__device__ __forceinline__ float sigm(float x) { return 1.0f / (1.0f + __expf(-x)); }
__device__ __forceinline__ float tanh_fast(float x) {
  x = fminf(15.0f, fmaxf(-15.0f, x));
  float e = __expf(2.0f * x);
  return (e - 1.0f) / (e + 1.0f);
}
__device__ __forceinline__ uint32_t umax_(uint32_t a, uint32_t b) {
  return a > b ? a : b;
}
__device__ __forceinline__ uintx4 umax4_(uintx4 a, uintx4 b) {
  uintx4 r;
  r.x = umax_(a.x, b.x); r.y = umax_(a.y, b.y);
  r.z = umax_(a.z, b.z); r.w = umax_(a.w, b.w);
  return r;
}

// ---------------------------------------------------------------------------
// Phase 0: pack weights (wxt transposed col-major, from round 3).
// ---------------------------------------------------------------------------
__global__ __launch_bounds__(256) void pack_kernel(
    const float* __restrict__ Wf, const float* __restrict__ Wi,
    const float* __restrict__ Wc, const float* __restrict__ Wo,
    const float* __restrict__ bf, const float* __restrict__ bi,
    const float* __restrict__ bc, const float* __restrict__ bo,
    unsigned short* __restrict__ whf, unsigned short* __restrict__ wxt,
    float* __restrict__ bias) {
  int idx = blockIdx.x * 256 + threadIdx.x;
  if (idx < 2048) {
    int g = idx >> 9, hid = idx & 511;
    const float* bp = (g == 0) ? bf : (g == 1) ? bi : (g == 2) ? bc : bo;
    bias[idx] = bp[hid];
  }
  int i2 = idx - 2048;
  if (i2 >= 0 && i2 < 256 * 2048) {
    int k = i2 >> 11, col = i2 & 2047, g = col >> 9, hid = col & 511;
    const float* Wp = (g == 0) ? Wf : (g == 1) ? Wi : (g == 2) ? Wc : Wo;
    wxt[(size_t)col * 256 + k] = f2bf(Wp[k * 512 + hid]);   // transposed
  }
  int i3 = i2 - 256 * 2048;
  if (i3 >= 0 && i3 < 1048576) {
    int j = i3 & 7, l = (i3 >> 3) & 63, ks = (i3 >> 9) & 15;
    int nt = (i3 >> 13) & 1, g = (i3 >> 14) & 3, cg = (i3 >> 16) & 15;
    int k = ks * 32 + (l >> 4) * 8 + j;
    int hid = cg * 32 + nt * 16 + (l & 15);
    const float* Wp = (g == 0) ? Wf : (g == 1) ? Wi : (g == 2) ? Wc : Wo;
    whf[i3] = f2bf(Wp[(256 + k) * 512 + hid]);
  }
}

// Init: h slot 0 = zeros (h0) on BOTH rails, c state = zeros.
__global__ __launch_bounds__(256) void init_kernel(uint32_t* h_ex,
                                                   uint32_t* h_l2,
                                                   float* c_gl) {
  int idx = blockIdx.x * 256 + threadIdx.x;
  if (idx < 65536) { h_ex[idx] = 0u; h_l2[idx] = 0u; }
  if (idx < 131072) c_gl[idx] = 0.0f;
}

// Poison: sentinel-fill all TCp1 slots EXCEPT the live one, on BOTH rails.
__global__ __launch_bounds__(256) void poison_kernel(uint32_t* h_ex,
                                                     uint32_t* h_l2, int live,
                                                     int TCp1) {
  size_t idx = (size_t)blockIdx.x * 256 + threadIdx.x;
  if (idx >= (size_t)TCp1 * 16384) return;
  int slot = (int)(idx >> 14);
  if (slot == live) return;
  ((uint4*)h_ex)[idx] = make_uint4(SENT, SENT, SENT, SENT);
  ((uint4*)h_l2)[idx] = make_uint4(SENT, SENT, SENT, SENT);
}

// ---------------------------------------------------------------------------
// Phase 1: Z = X @ Wx + bias (bf16 out). Round-3 version. Unchanged.
// ---------------------------------------------------------------------------
__global__ __launch_bounds__(256) void gemm_x(
    const float* __restrict__ X, const unsigned short* __restrict__ Wxt,
    const float* __restrict__ bias, unsigned short* __restrict__ Z,
    int t0, int TC, int tcs) {
  __shared__ __align__(16) unsigned short smem[17408];
  unsigned short* lds_a = smem;          // [ks8][row][8]
  unsigned short* lds_b = smem + 8192;   // [ks8][col][8]
  unsigned short* lds_t = smem;          // [row][136] epilogue

  const int tid = threadIdx.x;
  const int mt = blockIdx.x >> 4, ntb = blockIdx.x & 15;
  const int n0 = ntb * 128;
  const int w = tid >> 6, l = tid & 63, q = l >> 4, n15 = l & 15;

  floatx4 acc[2][8];
#pragma unroll
  for (int a = 0; a < 2; ++a)
#pragma unroll
    for (int nb = 0; nb < 8; ++nb) acc[a][nb] = (floatx4){0.f, 0.f, 0.f, 0.f};

  const int a_row = tid & 127, a_h = tid >> 7;
  const int Mr_st = mt * 128 + a_row;
  const int bb = Mr_st >> tcs, tt = Mr_st & (TC - 1);
  const float* asrc = X + ((size_t)(bb * T_SEQ + t0 + tt)) * I_SZ;

  for (int ko = 0; ko < 4; ++ko) {
    const int k0 = ko * 64;
    __syncthreads();
#pragma unroll
    for (int i = 0; i < 4; ++i) {
      int g = i * 256 + tid;
      int ks8 = g >> 7, col = g & 127;
      const unsigned short* gsrc =
          Wxt + (size_t)(n0 + col) * 256 + k0 + ks8 * 8;
      __builtin_amdgcn_global_load_lds(
          (const __attribute__((address_space(1))) void*)gsrc,
          (__attribute__((address_space(3))) void*)(lds_b + (size_t)g * 8),
          16, 0, 0);
    }
#pragma unroll
    for (int i = 0; i < 4; ++i) {
      int ks8 = 2 * i + a_h;
      int kl = ks8 * 8;
      float4 v0 = *(const float4*)(asrc + k0 + kl);
      float4 v1 = *(const float4*)(asrc + k0 + kl + 4);
      uint4 pk;
      pk.x = (uint32_t)f2bf(v0.x) | ((uint32_t)f2bf(v0.y) << 16);
      pk.y = (uint32_t)f2bf(v0.z) | ((uint32_t)f2bf(v0.w) << 16);
      pk.z = (uint32_t)f2bf(v1.x) | ((uint32_t)f2bf(v1.y) << 16);
      pk.w = (uint32_t)f2bf(v1.z) | ((uint32_t)f2bf(v1.w) << 16);
      *(uint4*)(lds_a + ((size_t)ks8 * 128 + a_row) * 8) = pk;
    }
    __syncthreads();
#pragma unroll
    for (int kk = 0; kk < 2; ++kk) {
      const int ks8 = kk * 4 + q;
      shortx8 af[2], bfr[8];
#pragma unroll
      for (int a = 0; a < 2; ++a) {
        int row = (w * 2 + a) * 16 + n15;
        af[a] = *(const shortx8*)(lds_a + ((size_t)ks8 * 128 + row) * 8);
      }
#pragma unroll
      for (int nb = 0; nb < 8; ++nb) {
        int col = nb * 16 + n15;
        bfr[nb] = *(const shortx8*)(lds_b + ((size_t)ks8 * 128 + col) * 8);
      }
#pragma unroll
      for (int a = 0; a < 2; ++a)
#pragma unroll
        for (int nb = 0; nb < 8; ++nb)
          acc[a][nb] = __builtin_amdgcn_mfma_f32_16x16x32_bf16(
              af[a], bfr[nb], acc[a][nb], 0, 0, 0);
    }
  }
  __syncthreads();
#pragma unroll
  for (int a = 0; a < 2; ++a) {
#pragma unroll
    for (int nb = 0; nb < 8; ++nb) {
      int colg = n0 + nb * 16 + n15;
      float bv = bias[colg];
      floatx4 v = acc[a][nb];
#pragma unroll
      for (int r = 0; r < 4; ++r) {
        int row = (w * 2 + a) * 16 + q * 4 + r;
        lds_t[row * 136 + nb * 16 + n15] = f2bf(v[r] + bv);
      }
    }
  }
  __syncthreads();
#pragma unroll
  for (int i = 0; i < 8; ++i) {
    int g2 = i * 256 + tid;
    int row = g2 >> 4, c8 = (g2 & 15) * 8;
    shortx8 v = *(const shortx8*)(lds_t + row * 136 + c8);
    int Mr2 = mt * 128 + row;
    *(shortx8*)(Z + (size_t)Mr2 * 2048 + n0 + c8) = v;
  }
}

// ---------------------------------------------------------------------------
// Phase 2: recurrent chunk — r6 skeleton (wave-split dual-rail poll, the
// verified 825 µs structure) + NEW: LDS peer-exchange of the polled
// fragments replaces the post-confirm global reload.
//  - wave w polls ONLY its own 4 chunks (16 KiB/block/round total — keeps
//    the bandwidth-fragile L2 rail uncongested; r7 showed 64 KiB/round
//    saturates the per-XCD L2 and is 1.7x WORSE than IC polling).
//  - alternation L2,L2,IC as r6 (placement-independent progress via IC).
//  - on confirm, the polled values ARE the Af fragments: wave w ds_writes
//    its 4 fragments to af_x[ks][lane], one barrier, then every wave
//    ds_reads all 16 — ~250cy instead of a 300-900cy global reload.
//    Mixed-rail confirms are fine (any non-SENT dword is final data).
//  - LDS = 128K weights + 16K gl + 16K af_x = exactly 160 KiB (1 block/CU).
// ---------------------------------------------------------------------------
__global__ __launch_bounds__(256, 1) void lstm_chunk(
    const unsigned short* __restrict__ Z, const unsigned short* __restrict__ whf,
    uint32_t* h_ex, uint32_t* h_l2, float* c_gl, int t0, int TC) {
  __shared__ unsigned short wlds[65536];   // 128 KiB weight panel
  __shared__ float gl[2][4][16][32];       // 16 KiB gate exchange (dbuf)
  __shared__ unsigned short af_x[8192];    // 16 KiB fragment exchange
  const int tid = threadIdx.x, l = tid & 63, w = tid >> 6, q = l >> 4,
            n15 = l & 15;
  // XCD-local relabel: peers of a bg group share blockIdx%8.
  const int idx = blockIdx.x;
  const int bg = (idx & 7) * 2 + ((idx >> 7) & 1);
  const int cg = (idx >> 3) & 15;

  __builtin_amdgcn_fence(__ATOMIC_ACQUIRE, "");  // drop stale L1/L2 lines

  {  // one-time: copy this block's contiguous 128 KiB panel into LDS
    const uint4* src = (const uint4*)(whf + (size_t)cg * 65536);
    uint4* dst = (uint4*)wlds;
#pragma unroll
    for (int i = 0; i < 32; ++i) dst[i * 256 + tid] = src[i * 256 + tid];
  }
  __syncthreads();

  const int m_e = tid >> 4, c2 = (tid & 15) * 2;
  const int b_e = bg * 16 + m_e;
  float cs0 = c_gl[b_e * 512 + cg * 32 + c2];
  float cs1 = c_gl[b_e * 512 + cg * 32 + c2 + 1];

  const unsigned short* wb0 = wlds + w * 16384;  // [ks][lane][8], nt=0
  const unsigned short* wb1 = wb0 + 8192;        // nt=1
  const int TCp1 = TC + 1;
  int sr = t0 % TCp1;  // read slot for step t

  // per-lane element offset (shorts) of Af ks=0 within a slot; ks-stride=512
  const size_t afoff = ((size_t)(bg * 64 + q) * 16 + n15) * 8;

  for (int t = t0; t < t0 + TC; ++t) {
    int sw = sr + 1;
    if (sw == TCp1) sw = 0;
    // Z prefetch (cached; issued before the poll, waited inside it)
    float zv[8];
#pragma unroll
    for (int nt = 0; nt < 2; ++nt)
#pragma unroll
      for (int r = 0; r < 4; ++r)
        zv[nt * 4 + r] =
            bf2f(Z[((size_t)(bg * 16 + q * 4 + r) * TC + (t - t0)) * 2048 +
                   w * 512 + cg * 32 + nt * 16 + n15]);
    // B prefetch ks 0..7 (LDS; overlaps the poll)
    shortx8 bp0[8], bp1[8];
#pragma unroll
    for (int ks = 0; ks < 8; ++ks) {
      bp0[ks] = *(const shortx8*)(wb0 + ks * 512 + l * 8);
      bp1[ks] = *(const shortx8*)(wb1 + ks * 512 + l * 8);
    }

    // ---- wave-split dual-rail poll over OWN 4 chunks (r6 verified) ----
    const unsigned short* sl_ic =
        (const unsigned short*)(h_ex + (size_t)sr * 65536);
    const unsigned short* sl_l2 =
        (const unsigned short*)(h_l2 + (size_t)sr * 65536);
    const unsigned short* pwic = sl_ic + afoff + (size_t)w * 2048;
    const unsigned short* pwl2 = sl_l2 + afoff + (size_t)w * 2048;
    uintx4 P0, P1, P2, P3;
    uint32_t mx;
    int round = 0;
    for (;;) {
      if ((round % 3) != 2) {  // L2-rail round (sc0: bypass L1, hit L2)
        asm volatile(
            "global_load_dwordx4 %0, %4, off sc0\n\t"
            "global_load_dwordx4 %1, %4, off offset:1024 sc0\n\t"
            "global_load_dwordx4 %2, %4, off offset:2048 sc0\n\t"
            "global_load_dwordx4 %3, %4, off offset:3072 sc0\n\t"
            "s_waitcnt vmcnt(0)"
            : "=v"(P0), "=v"(P1), "=v"(P2), "=v"(P3)
            : "v"(pwl2)
            : "memory");
      } else {                 // IC-rail round (guaranteed progress)
        asm volatile(
            "global_load_dwordx4 %0, %4, off sc0 sc1\n\t"
            "global_load_dwordx4 %1, %4, off offset:1024 sc0 sc1\n\t"
            "global_load_dwordx4 %2, %4, off offset:2048 sc0 sc1\n\t"
            "global_load_dwordx4 %3, %4, off offset:3072 sc0 sc1\n\t"
            "s_waitcnt vmcnt(0)"
            : "=v"(P0), "=v"(P1), "=v"(P2), "=v"(P3)
            : "v"(pwic)
            : "memory");
      }
      uintx4 m = umax4_(umax4_(P0, P1), umax4_(P2, P3));
      mx = umax_(umax_(m.x, m.y), umax_(m.z, m.w));
      if (!__any(mx == SENT)) break;
      ++round;
    }
    // ---- LDS peer-exchange: publish own 4 fragments, read all 16 ----
    *(uintx4*)(af_x + ((size_t)(4 * w + 0) * 64 + l) * 8) = P0;
    *(uintx4*)(af_x + ((size_t)(4 * w + 1) * 64 + l) * 8) = P1;
    *(uintx4*)(af_x + ((size_t)(4 * w + 2) * 64 + l) * 8) = P2;
    *(uintx4*)(af_x + ((size_t)(4 * w + 3) * 64 + l) * 8) = P3;
    __syncthreads();  // all 16 fragments visible block-wide

    floatx4 a0 = (floatx4){0.f, 0.f, 0.f, 0.f};
    floatx4 a1 = (floatx4){0.f, 0.f, 0.f, 0.f};
#pragma unroll
    for (int ks = 0; ks < 8; ++ks) {
      shortx8 af = *(const shortx8*)(af_x + ((size_t)ks * 64 + l) * 8);
      a0 = __builtin_amdgcn_mfma_f32_16x16x32_bf16(af, bp0[ks], a0, 0, 0, 0);
      a1 = __builtin_amdgcn_mfma_f32_16x16x32_bf16(af, bp1[ks], a1, 0, 0, 0);
    }
#pragma unroll
    for (int ks = 8; ks < 16; ++ks) {
      shortx8 af = *(const shortx8*)(af_x + ((size_t)ks * 64 + l) * 8);
      shortx8 tb0 = *(const shortx8*)(wb0 + ks * 512 + l * 8);
      shortx8 tb1 = *(const shortx8*)(wb1 + ks * 512 + l * 8);
      a0 = __builtin_amdgcn_mfma_f32_16x16x32_bf16(af, tb0, a0, 0, 0, 0);
      a1 = __builtin_amdgcn_mfma_f32_16x16x32_bf16(af, tb1, a1, 0, 0, 0);
    }
    // gate nonlinearity, publish to LDS (buffer t&1)
    const int pb = t & 1;
#pragma unroll
    for (int i = 0; i < 8; ++i) {
      float x = ((i < 4) ? a0[i & 3] : a1[i & 3]) + zv[i];
      float gv = (w == 2) ? tanh_fast(x) : sigm(x);
      gl[pb][w][q * 4 + (i & 3)][(i >> 2) * 16 + n15] = gv;
    }
    __syncthreads();
    {
      float f0 = gl[pb][0][m_e][c2], f1 = gl[pb][0][m_e][c2 + 1];
      float i0 = gl[pb][1][m_e][c2], i1 = gl[pb][1][m_e][c2 + 1];
      float g0 = gl[pb][2][m_e][c2], g1 = gl[pb][2][m_e][c2 + 1];
      float o0 = gl[pb][3][m_e][c2], o1 = gl[pb][3][m_e][c2 + 1];
      cs0 = f0 * cs0 + i0 * g0;
      cs1 = f1 * cs1 + i1 * g1;
      float h0 = o0 * tanh_fast(cs0);
      float h1 = o1 * tanh_fast(cs1);
      uint32_t hw = (uint32_t)f2bf(h0) | ((uint32_t)f2bf(h1) << 16);
      size_t widx = (size_t)sw * 65536 +
                    (size_t)(((bg * 16 + cg) * 4 + (c2 >> 3)) * 16 + m_e) * 4 +
                    ((c2 & 7) >> 1);
      // rail 2: plain write-back store — updates the local L2 line
      uint32_t* pl2w = h_l2 + widx;
      asm volatile("global_store_dword %0, %1, off"
                   :
                   : "v"(pl2w), "v"(hw)
                   : "memory");
      // rail 1: IC (system scope, guaranteed) — escalation + out_kernel path
      __hip_atomic_store(h_ex + widx, hw, __ATOMIC_RELAXED,
                         __HIP_MEMORY_SCOPE_SYSTEM);
    }
    sr = sw;
  }
  c_gl[b_e * 512 + cg * 32 + c2] = cs0;
  c_gl[b_e * 512 + cg * 32 + c2 + 1] = cs1;
}

// ---------------------------------------------------------------------------
// Phase 3: logits + log_softmax (reads final h slot on the IC rail).
// ---------------------------------------------------------------------------
__global__ __launch_bounds__(256) void out_kernel(
    const uint32_t* __restrict__ hfin, const float* __restrict__ Wout,
    const float* __restrict__ bout, float* __restrict__ out) {
  const int b = blockIdx.x, tid = threadIdx.x;
  __shared__ float hrow[512];
  if (tid < 64) {
    int ks = tid >> 2, qq = tid & 3;
    const uint4* h4 = (const uint4*)hfin;
    uint4 v = h4[((((size_t)(b >> 4)) * 16 + ks) * 4 + qq) * 16 + (b & 15)];
    uint32_t u[4] = {v.x, v.y, v.z, v.w};
#pragma unroll
    for (int d = 0; d < 4; ++d) {
      hrow[ks * 32 + qq * 8 + d * 2] = bf2f((unsigned short)(u[d] & 0xffff));
      hrow[ks * 32 + qq * 8 + d * 2 + 1] = bf2f((unsigned short)(u[d] >> 16));
    }
  }
  __syncthreads();
  float acc = bout[tid];
  for (int k = 0; k < 512; ++k) acc += hrow[k] * Wout[k * 256 + tid];
  __shared__ float red[256];
  red[tid] = acc;
  __syncthreads();
  for (int s = 128; s > 0; s >>= 1) {
    if (tid < s) red[tid] = fmaxf(red[tid], red[tid + s]);
    __syncthreads();
  }
  float mx = red[0];
  __syncthreads();
  red[tid] = __expf(acc - mx);
  __syncthreads();
  for (int s = 128; s > 0; s >>= 1) {
    if (tid < s) red[tid] += red[tid + s];
    __syncthreads();
  }
  out[b * 256 + tid] = acc - mx - logf(red[0]);
}

// ---------------------------------------------------------------------------
extern "C" void kernel_launch(void* const* d_in, const int* in_sizes, int n_in,
                              void* d_out, int out_size, void* d_ws,
                              size_t ws_size, hipStream_t stream) {
  const float* X = (const float*)d_in[0];
  const float* Wf = (const float*)d_in[1];
  const float* bf = (const float*)d_in[2];
  const float* Wi = (const float*)d_in[3];
  const float* bi = (const float*)d_in[4];
  const float* Wc = (const float*)d_in[5];
  const float* bc = (const float*)d_in[6];
  const float* Wo = (const float*)d_in[7];
  const float* bo = (const float*)d_in[8];
  const float* Wout = (const float*)d_in[9];
  const float* bout = (const float*)d_in[10];

  char* ws = (char*)d_ws;
  unsigned short* whf = (unsigned short*)(ws + 0x000000);   // 2 MiB
  unsigned short* wxt = (unsigned short*)(ws + 0x200000);   // 1 MiB (transposed)
  float* bias = (float*)(ws + 0x300000);                    // 8 KiB
  float* c_gl = (float*)(ws + 0x310000);                    // 512 KiB
  uint32_t* h_ex = (uint32_t*)(ws + 0x400000);              // 257 x 256 KiB (IC rail)
  uint32_t* h_l2 = (uint32_t*)(ws + 0x4500000);             // 257 x 256 KiB (L2 rail)
  const size_t zoff = 0x8600000;                            // 134 MiB
  unsigned short* Z = (unsigned short*)(ws + zoff);         // TC MiB

  int TC = 256;
  while (TC > 16 && zoff + ((size_t)B_SZ * TC * 2048 * 2) > ws_size) TC >>= 1;
  int tcs = 0;
  while ((1 << tcs) < TC) ++tcs;
  const int TCp1 = TC + 1;

  pack_kernel<<<(2048 + 256 * 2048 + 1048576 + 255) / 256, 256, 0, stream>>>(
      Wf, Wi, Wc, Wo, bf, bi, bc, bo, whf, wxt, bias);
  init_kernel<<<512, 256, 0, stream>>>(h_ex, h_l2, c_gl);

  for (int t0 = 0; t0 < T_SEQ; t0 += TC) {
    poison_kernel<<<(TCp1 * 16384 + 255) / 256, 256, 0, stream>>>(
        h_ex, h_l2, t0 % TCp1, TCp1);
    gemm_x<<<(B_SZ * TC / 128) * 16, 256, 0, stream>>>(X, wxt, bias, Z, t0, TC,
                                                       tcs);
    lstm_chunk<<<256, 256, 0, stream>>>(Z, whf, h_ex, h_l2, c_gl, t0, TC);
  }
  const int sfin = T_SEQ % TCp1;
  out_kernel<<<256, 256, 0, stream>>>(h_ex + (size_t)sfin * 65536, Wout, bout,
                                      (float*)d_out);
}